// Round 12
// baseline (261.809 us; speedup 1.0000x reference)
//
#include <hip/hip_runtime.h>
#include <cstdint>
#include <cstddef>

typedef unsigned short u16;
typedef __attribute__((ext_vector_type(8))) __bf16 bf16x8;
typedef __attribute__((ext_vector_type(4))) float f32x4;

__device__ __forceinline__ u16 f2bf(float f) {
  unsigned u = __float_as_uint(f);
  u += 0x7FFFu + ((u >> 16) & 1u);   // round-to-nearest-even
  return (u16)(u >> 16);
}

__device__ __forceinline__ float bf2f(u16 h) {
  return __uint_as_float(((unsigned)h) << 16);
}

__device__ __forceinline__ void async16(u16* lds, const u16* g) {
  __builtin_amdgcn_global_load_lds(
      (const __attribute__((address_space(1))) unsigned int*)g,
      (__attribute__((address_space(3))) unsigned int*)lds, 16, 0, 0);
}

// ---------------- prep: x->bf16 (blocks 0..3071) + TT pre-pass (blocks 3072..4295) ----
__global__ __launch_bounds__(256)
void prep(const float4* __restrict__ x4, ushort4* __restrict__ xb4,
          const float* __restrict__ gA1, const float* __restrict__ gB1,
          const float* __restrict__ gC1, const float* __restrict__ gD1,
          const float* __restrict__ gA2, const float* __restrict__ gB2,
          const float* __restrict__ gC2, const float* __restrict__ gD2,
          float* __restrict__ B12_1, float* __restrict__ B12_2,
          float* __restrict__ C1, float* __restrict__ C2) {
  const int b = blockIdx.x;
  const int tid = threadIdx.x;
  if (b < 3072) {
    int i = b * 256 + tid;
    float4 v = x4[i];
    ushort4 o;
    o.x = f2bf(v.x); o.y = f2bf(v.y); o.z = f2bf(v.z); o.w = f2bf(v.w);
    xb4[i] = o;
    return;
  }
  int idx = (b - 3072) * 256 + tid;
  if (idx < 9216) {
    int e = idx;
    int r2 = e % 24; int t = e / 24;
    int fo12 = t % 24, fi12 = t / 24;
    int i2 = fi12 % 4, i1 = fi12 / 4;
    int o2 = fo12 % 6, o1 = fo12 / 6;
    float s = 0.f;
#pragma unroll
    for (int r1 = 0; r1 < 12; ++r1)
      s += gA1[(i1 * 4 + o1) * 12 + r1] * gB1[((r1 * 4 + i2) * 6 + o2) * 24 + r2];
    B12_1[e] = s;
  } else if (idx < 18432) {
    int e = idx - 9216;
    int r2 = e % 24; int t = e / 24;
    int fo12 = t % 16, fi12 = t / 16;
    int i2 = fi12 % 6, i1 = fi12 / 6;
    int o2 = fo12 % 4, o1 = fo12 / 4;
    float s = 0.f;
#pragma unroll
    for (int r1 = 0; r1 < 12; ++r1)
      s += gA2[(i1 * 4 + o1) * 12 + r1] * gB2[((r1 * 6 + i2) * 4 + o2) * 24 + r2];
    B12_2[e] = s;
  } else if (idx < 165888) {
    int e = idx - 18432;
    int fi34 = e % 48; int t = e / 48;
    int fo34 = t % 128;
    int i3 = fi34 / 8, i4 = fi34 % 8;
    int o3 = fo34 / 16, o4 = fo34 % 16;
    int r2 = t / 128;
    float s = 0.f;
#pragma unroll
    for (int r3 = 0; r3 < 12; ++r3)
      s += gC1[((r2 * 6 + i3) * 8 + o3) * 12 + r3] * gD1[(r3 * 8 + i4) * 16 + o4];
    C1[e] = s;
  } else {
    int e = idx - 165888;
    int fi34 = e % 128; int t = e / 128;
    int fo34 = t % 48;
    int i3 = fi34 / 16, i4 = fi34 % 16;
    int o3 = fo34 / 8, o4 = fo34 % 8;
    int r2 = t / 48;
    float s = 0.f;
#pragma unroll
    for (int r3 = 0; r3 < 12; ++r3)
      s += gC2[((r2 * 8 + i3) * 6 + o3) * 12 + r3] * gD2[(r3 * 16 + i4) * 8 + o4];
    C2[e] = s;
  }
}

// ---------------- TT expand (device body): Wt[out][in] = sum_r2 B12*C34t ----------------
template <int FI12, int I34, int O12, int O34, int OG>
__device__ __forceinline__
void tt_expand_body(const float* __restrict__ B12, const float* __restrict__ C34t,
                    u16* __restrict__ Wt, int bx, int by, int tid, float* sB) {
  constexpr int R2 = 24;
  constexpr int Kin = FI12 * I34;
  constexpr int IC = Kin / 8;
  constexpr int I34C = I34 / 8;
  for (int e = tid; e < FI12 * OG * R2; e += 256) {
    int r2 = e % R2; int t = e / R2;
    int f = t % OG; int fi12 = t / OG;
    sB[(fi12 * OG + f) * 25 + r2] = B12[(fi12 * O12 + by * OG + f) * R2 + r2];
  }
  __syncthreads();
  const int t = bx * 256 + tid;
  const int fo34 = t / IC;
  const int ic = t % IC;
  const int fi12 = ic / I34C;
  const int fi34 = (ic % I34C) * 8;

  float acc[OG][8];
#pragma unroll
  for (int f = 0; f < OG; ++f)
#pragma unroll
    for (int k = 0; k < 8; ++k) acc[f][k] = 0.f;

  for (int r2 = 0; r2 < R2; ++r2) {
    const float4* cp = (const float4*)(C34t + ((size_t)(r2 * O34 + fo34) * I34 + fi34));
    float4 c0 = cp[0], c1 = cp[1];
    float c[8] = {c0.x, c0.y, c0.z, c0.w, c1.x, c1.y, c1.z, c1.w};
#pragma unroll
    for (int f = 0; f < OG; ++f) {
      float bb = sB[(fi12 * OG + f) * 25 + r2];
#pragma unroll
      for (int k = 0; k < 8; ++k) acc[f][k] += bb * c[k];
    }
  }
#pragma unroll
  for (int f = 0; f < OG; ++f) {
    int out = (by * OG + f) * O34 + fo34;
    u16 v[8];
#pragma unroll
    for (int k = 0; k < 8; ++k) v[k] = f2bf(acc[f][k]);
    *(uint4*)(Wt + (size_t)out * Kin + fi12 * I34 + fi34) = *(const uint4*)v;
  }
}

// Merged: blocks 0..287 -> layer1 (48x6); blocks 288..575 -> layer2 (72x4)
__global__ __launch_bounds__(256)
void tt_expand2(const float* __restrict__ B12_1, const float* __restrict__ C1, u16* __restrict__ W1t,
                const float* __restrict__ B12_2, const float* __restrict__ C2, u16* __restrict__ W2t) {
  __shared__ float sB[24 * 4 * 25];
  const int b = blockIdx.x;
  const int tid = threadIdx.x;
  if (b < 288) {
    tt_expand_body<16, 48, 24, 128, 4>(B12_1, C1, W1t, b % 48, b / 48, tid, sB);
  } else {
    int bb = b - 288;
    tt_expand_body<24, 128, 16, 48, 4>(B12_2, C2, W2t, bb % 72, bb / 72, tid, sB);
  }
}

// out = bias2 + sum of nz bf16 partials; 8 elems/thread, 16B partial loads
__global__ void reduceN8(const uint4* __restrict__ P, const float* __restrict__ bias,
                         float4* __restrict__ out4, int n8, int zstride8, int nz) {
  int i = blockIdx.x * 256 + threadIdx.x;
  if (i >= n8) return;
  int b0 = (i % 96) * 8;
  float a[8];
#pragma unroll
  for (int k = 0; k < 8; ++k) a[k] = bias[b0 + k];
  for (int s = 0; s < nz; ++s) {
    uint4 u = P[i + s * zstride8];
    const u16* up = (const u16*)&u;
#pragma unroll
    for (int k = 0; k < 8; ++k) a[k] += bf2f(up[k]);
  }
  out4[i * 2]     = (float4){a[0], a[1], a[2], a[3]};
  out4[i * 2 + 1] = (float4){a[4], a[5], a[6], a[7]};
}

// ---------------- bf16 MFMA GEMM, C = A(MxK) * Bt(NxK)^T, 64x128 tile ----------------
// R11: latency-bound (1970 cyc/block-iter vs 78 MFMA; Occ 26% = 3 blocks/CU at
// 132 regs). Fix: halve M-tile -> acc 32 AGPR, ~100 total regs -> ~5 blocks/CU
// resident; more out-of-phase blocks hide each block's barrier vmcnt drain.
// Keeps R11's B-direct-from-L2 (bank conflicts halved) + dbuf A (R9 win) +
// j-inner epilogue (R7/R8 A/B). MINW=4 (cap 128; MINW>=5-with-overrun spills,
// R5: 409MB scratch). Wave layout: 2x2 over (64 rows, 128 cols).
template <bool GELU>
__global__ __launch_bounds__(256, 4)
void gemm_bt(const u16* __restrict__ A, const u16* __restrict__ Bt,
             const float* __restrict__ bias, u16* __restrict__ Out,
             int N, int K, int klen, size_t zstride) {
  __shared__ __align__(16) u16 As[2][64 * 32];
  const int tid = threadIdx.x;
  const int bm = blockIdx.x, bn = blockIdx.y;
  const int wave = tid >> 6, lane = tid & 63;
  const int wm = (wave & 1) * 32, wn = (wave >> 1) * 64;
  const int lr = lane & 15, lq = lane >> 4;

  const int srow = tid >> 2;           // 0..63
  const int scol = (tid & 3) * 8;
  const u16* Ag = A + (size_t)(bm * 64 + srow) * K + scol;
  // direct-from-L2 B fragments: 16B/lane, 16 rows x 64B fully-used sectors
  const u16* Bg = Bt + (size_t)(bn * 128 + wn + lr) * K + lq * 8;
  u16* AsW = &As[0][0] + tid * 8;

  f32x4 acc[2][4];
#pragma unroll
  for (int i = 0; i < 2; i++)
#pragma unroll
    for (int j = 0; j < 4; j++) acc[i][j] = (f32x4){0.f, 0.f, 0.f, 0.f};

  auto stageA = [&](int buf, int k0) {
    async16(AsW + buf * 2048, Ag + k0);
  };
  auto loadB = [&](bf16x8* b, int k0) {
#pragma unroll
    for (int j = 0; j < 4; j++)
      b[j] = *(const bf16x8*)(Bg + (size_t)(j * 16) * K + k0);
  };
  auto compute = [&](int buf, const bf16x8* b) {
    bf16x8 af[2];
#pragma unroll
    for (int i = 0; i < 2; i++)
      af[i] = *(const bf16x8*)(&As[buf][0] + (wm + i * 16 + lr) * 32 + lq * 8);
#pragma unroll
    for (int i = 0; i < 2; i++)
#pragma unroll
      for (int j = 0; j < 4; j++)
        acc[i][j] = __builtin_amdgcn_mfma_f32_16x16x32_bf16(af[i], b[j], acc[i][j], 0, 0, 0);
  };

  const int kbeg = blockIdx.z * klen;
  const int nIter = klen >> 5;   // even (>=12)
  bf16x8 b0[4], b1[4];
  stageA(0, kbeg);
  loadB(b0, kbeg);
  for (int it = 0; it < nIter; it += 2) {
    __syncthreads();                 // As[0] staged; As[1] readers done
    if (it + 1 < nIter) { stageA(1, kbeg + (it + 1) * 32); loadB(b1, kbeg + (it + 1) * 32); }
    compute(0, b0);
    __syncthreads();                 // As[1] staged; As[0] readers done
    if (it + 2 < nIter) { stageA(0, kbeg + (it + 2) * 32); loadB(b0, kbeg + (it + 2) * 32); }
    compute(1, b1);
  }

  u16* Op = Out + blockIdx.z * zstride;
  // C/D layout: col = lane&15, row = (lane>>4)*4 + reg  [verified m89/m91]
  const int r0 = bm * 64 + wm + lq * 4;
  const int c0 = bn * 128 + wn + lr;
  float bv[4];
  if (GELU) {
#pragma unroll
    for (int j = 0; j < 4; j++) bv[j] = bias[c0 + j * 16];
  }
#pragma unroll
  for (int i = 0; i < 2; i++) {
#pragma unroll
    for (int r = 0; r < 4; r++) {
      const size_t rowoff = (size_t)(r0 + i * 16 + r) * N;
#pragma unroll
      for (int j = 0; j < 4; j++) {
        float v = acc[i][j][r];
        if (GELU) {
          v += bv[j];
          v = 0.5f * v * (1.f + erff(v * 0.70710678118654752f));
        }
        Op[rowoff + c0 + j * 16] = f2bf(v);
      }
    }
  }
}

extern "C" void kernel_launch(void* const* d_in, const int* in_sizes, int n_in,
                              void* d_out, int out_size, void* d_ws, size_t ws_size,
                              hipStream_t stream) {
  const float* x   = (const float*)d_in[0];
  const float* g1a = (const float*)d_in[1];
  const float* g1b = (const float*)d_in[2];
  const float* g1c = (const float*)d_in[3];
  const float* g1d = (const float*)d_in[4];
  const float* b1  = (const float*)d_in[5];
  const float* g2a = (const float*)d_in[6];
  const float* g2b = (const float*)d_in[7];
  const float* g2c = (const float*)d_in[8];
  const float* g2d = (const float*)d_in[9];
  const float* b2  = (const float*)d_in[10];
  float* out = (float*)d_out;

  char* ws = (char*)d_ws;
  u16* xb   = (u16*)(ws + 0);          // 4096x768 bf16   = 6291456 B
  u16* W1t  = (u16*)(ws + 6291456);    // 3072x768 bf16   = 4718592 B
  u16* W2t  = (u16*)(ws + 11010048);   // 768x3072 bf16   = 4718592 B
  u16* h    = (u16*)(ws + 15728640);   // 4096x3072 bf16  = 25165824 B
  u16* Part = (u16*)(ws + 40894464);   // nz x 4096x768 bf16
  // TT scratch ALIASES Part (dead before gemm2 writes Part; stream-ordered)
  float* B12_1 = (float*)(ws + 40894464);            // 9216 f32
  float* B12_2 = (float*)(ws + 40894464 + 36864);    // 9216 f32
  float* C1    = (float*)(ws + 40894464 + 73728);    // 147456 f32
  float* C2    = (float*)(ws + 40894464 + 663552);   // 147456 f32

  // split-K factor for GEMM2, guarded by workspace size
  const int nz = (ws_size >= 40894464ull + 8ull * 6291456ull) ? 8 : 4;

  // x->bf16 (blocks 0..3071) + TT pre-pass (blocks 3072..4295)
  prep<<<4296, 256, 0, stream>>>((const float4*)x, (ushort4*)xb,
                                 g1a, g1b, g1c, g1d, g2a, g2b, g2c, g2d,
                                 B12_1, B12_2, C1, C2);

  // merged expand: layer1 (blocks 0..287) + layer2 (blocks 288..575)
  tt_expand2<<<576, 256, 0, stream>>>(B12_1, C1, W1t, B12_2, C2, W2t);

  // GEMM1: h = gelu(x @ W1 + b1)   (4096 x 3072, K=768), 1536 blocks
  gemm_bt<true><<<dim3(64, 24, 1), 256, 0, stream>>>(xb, W1t, b1, h, 3072, 768, 768, 0);
  // GEMM2: bf16 partials, K=3072 split nz ways; nz=8 -> 3072 blocks, 12 iters
  gemm_bt<false><<<dim3(64, 6, nz), 256, 0, stream>>>(h, W2t, nullptr, Part,
                                                      768, 3072, 3072 / nz, 3145728);
  // out = b2 + sum(partials)
  reduceN8<<<1536, 256, 0, stream>>>((const uint4*)Part, b2,
                                     (float4*)out, 393216, 393216, nz);
}

// Round 13
// 258.102 us; speedup vs baseline: 1.0144x; 1.0144x over previous
//
#include <hip/hip_runtime.h>
#include <cstdint>
#include <cstddef>

typedef unsigned short u16;
typedef __attribute__((ext_vector_type(8))) __bf16 bf16x8;
typedef __attribute__((ext_vector_type(4))) float f32x4;

__device__ __forceinline__ u16 f2bf(float f) {
  unsigned u = __float_as_uint(f);
  u += 0x7FFFu + ((u >> 16) & 1u);   // round-to-nearest-even
  return (u16)(u >> 16);
}

__device__ __forceinline__ float bf2f(u16 h) {
  return __uint_as_float(((unsigned)h) << 16);
}

// ---------------- prep: x->bf16 (blocks 0..3071) + TT pre-pass (blocks 3072..4295) ----
__global__ __launch_bounds__(256)
void prep(const float4* __restrict__ x4, ushort4* __restrict__ xb4,
          const float* __restrict__ gA1, const float* __restrict__ gB1,
          const float* __restrict__ gC1, const float* __restrict__ gD1,
          const float* __restrict__ gA2, const float* __restrict__ gB2,
          const float* __restrict__ gC2, const float* __restrict__ gD2,
          float* __restrict__ B12_1, float* __restrict__ B12_2,
          float* __restrict__ C1, float* __restrict__ C2) {
  const int b = blockIdx.x;
  const int tid = threadIdx.x;
  if (b < 3072) {
    int i = b * 256 + tid;
    float4 v = x4[i];
    ushort4 o;
    o.x = f2bf(v.x); o.y = f2bf(v.y); o.z = f2bf(v.z); o.w = f2bf(v.w);
    xb4[i] = o;
    return;
  }
  int idx = (b - 3072) * 256 + tid;
  if (idx < 9216) {
    int e = idx;
    int r2 = e % 24; int t = e / 24;
    int fo12 = t % 24, fi12 = t / 24;
    int i2 = fi12 % 4, i1 = fi12 / 4;
    int o2 = fo12 % 6, o1 = fo12 / 6;
    float s = 0.f;
#pragma unroll
    for (int r1 = 0; r1 < 12; ++r1)
      s += gA1[(i1 * 4 + o1) * 12 + r1] * gB1[((r1 * 4 + i2) * 6 + o2) * 24 + r2];
    B12_1[e] = s;
  } else if (idx < 18432) {
    int e = idx - 9216;
    int r2 = e % 24; int t = e / 24;
    int fo12 = t % 16, fi12 = t / 16;
    int i2 = fi12 % 6, i1 = fi12 / 6;
    int o2 = fo12 % 4, o1 = fo12 / 4;
    float s = 0.f;
#pragma unroll
    for (int r1 = 0; r1 < 12; ++r1)
      s += gA2[(i1 * 4 + o1) * 12 + r1] * gB2[((r1 * 6 + i2) * 4 + o2) * 24 + r2];
    B12_2[e] = s;
  } else if (idx < 165888) {
    int e = idx - 18432;
    int fi34 = e % 48; int t = e / 48;
    int fo34 = t % 128;
    int i3 = fi34 / 8, i4 = fi34 % 8;
    int o3 = fo34 / 16, o4 = fo34 % 16;
    int r2 = t / 128;
    float s = 0.f;
#pragma unroll
    for (int r3 = 0; r3 < 12; ++r3)
      s += gC1[((r2 * 6 + i3) * 8 + o3) * 12 + r3] * gD1[(r3 * 8 + i4) * 16 + o4];
    C1[e] = s;
  } else {
    int e = idx - 165888;
    int fi34 = e % 128; int t = e / 128;
    int fo34 = t % 48;
    int i3 = fi34 / 16, i4 = fi34 % 16;
    int o3 = fo34 / 8, o4 = fo34 % 8;
    int r2 = t / 48;
    float s = 0.f;
#pragma unroll
    for (int r3 = 0; r3 < 12; ++r3)
      s += gC2[((r2 * 8 + i3) * 6 + o3) * 12 + r3] * gD2[(r3 * 16 + i4) * 8 + o4];
    C2[e] = s;
  }
}

// ---------------- TT expand (device body): Wt[out][in] = sum_r2 B12*C34t ----------------
template <int FI12, int I34, int O12, int O34, int OG>
__device__ __forceinline__
void tt_expand_body(const float* __restrict__ B12, const float* __restrict__ C34t,
                    u16* __restrict__ Wt, int bx, int by, int tid, float* sB) {
  constexpr int R2 = 24;
  constexpr int Kin = FI12 * I34;
  constexpr int IC = Kin / 8;
  constexpr int I34C = I34 / 8;
  for (int e = tid; e < FI12 * OG * R2; e += 256) {
    int r2 = e % R2; int t = e / R2;
    int f = t % OG; int fi12 = t / OG;
    sB[(fi12 * OG + f) * 25 + r2] = B12[(fi12 * O12 + by * OG + f) * R2 + r2];
  }
  __syncthreads();
  const int t = bx * 256 + tid;
  const int fo34 = t / IC;
  const int ic = t % IC;
  const int fi12 = ic / I34C;
  const int fi34 = (ic % I34C) * 8;

  float acc[OG][8];
#pragma unroll
  for (int f = 0; f < OG; ++f)
#pragma unroll
    for (int k = 0; k < 8; ++k) acc[f][k] = 0.f;

  for (int r2 = 0; r2 < R2; ++r2) {
    const float4* cp = (const float4*)(C34t + ((size_t)(r2 * O34 + fo34) * I34 + fi34));
    float4 c0 = cp[0], c1 = cp[1];
    float c[8] = {c0.x, c0.y, c0.z, c0.w, c1.x, c1.y, c1.z, c1.w};
#pragma unroll
    for (int f = 0; f < OG; ++f) {
      float bb = sB[(fi12 * OG + f) * 25 + r2];
#pragma unroll
      for (int k = 0; k < 8; ++k) acc[f][k] += bb * c[k];
    }
  }
#pragma unroll
  for (int f = 0; f < OG; ++f) {
    int out = (by * OG + f) * O34 + fo34;
    u16 v[8];
#pragma unroll
    for (int k = 0; k < 8; ++k) v[k] = f2bf(acc[f][k]);
    *(uint4*)(Wt + (size_t)out * Kin + fi12 * I34 + fi34) = *(const uint4*)v;
  }
}

// Merged: blocks 0..287 -> layer1 (48x6); blocks 288..575 -> layer2 (72x4)
__global__ __launch_bounds__(256)
void tt_expand2(const float* __restrict__ B12_1, const float* __restrict__ C1, u16* __restrict__ W1t,
                const float* __restrict__ B12_2, const float* __restrict__ C2, u16* __restrict__ W2t) {
  __shared__ float sB[24 * 4 * 25];
  const int b = blockIdx.x;
  const int tid = threadIdx.x;
  if (b < 288) {
    tt_expand_body<16, 48, 24, 128, 4>(B12_1, C1, W1t, b % 48, b / 48, tid, sB);
  } else {
    int bb = b - 288;
    tt_expand_body<24, 128, 16, 48, 4>(B12_2, C2, W2t, bb % 72, bb / 72, tid, sB);
  }
}

// out = bias2 + sum of nz bf16 partials; 8 elems/thread, 16B partial loads
__global__ void reduceN8(const uint4* __restrict__ P, const float* __restrict__ bias,
                         float4* __restrict__ out4, int n8, int zstride8, int nz) {
  int i = blockIdx.x * 256 + threadIdx.x;
  if (i >= n8) return;
  int b0 = (i % 96) * 8;
  float a[8];
#pragma unroll
  for (int k = 0; k < 8; ++k) a[k] = bias[b0 + k];
  for (int s = 0; s < nz; ++s) {
    uint4 u = P[i + s * zstride8];
    const u16* up = (const u16*)&u;
#pragma unroll
    for (int k = 0; k < 8; ++k) a[k] += bf2f(up[k]);
  }
  out4[i * 2]     = (float4){a[0], a[1], a[2], a[3]};
  out4[i * 2 + 1] = (float4){a[4], a[5], a[6], a[7]};
}

// ---------------- bf16 MFMA GEMM, C = A(MxK) * Bt(NxK)^T, 128x128, NO LDS/BARRIER ----
// R9-R12 invariant: ~1333-1970 cyc per block-iter regardless of tile = the
// per-iter s_waitcnt vmcnt(0)+s_barrier drain (m97-structure stall). Fix:
// both A and B fragments load DIRECTLY from global (L2/L3-hot) in the exact
// MFMA register layout; no LDS, no __syncthreads in the K-loop. Compiler is
// then free to emit fine-grained vmcnt(N) (AITER-style) across the manual
// register double-buffer (prefetch next iter's 8 frags during current MFMAs).
// Regs: 64 frag VGPR + 64 acc + addr ~= 145 -> 3 blocks/CU (MINW=3; MINW>=5
// spills acc, R5). Epilogue j-innermost (R7/R8 same-chip A/B).
template <bool GELU>
__global__ __launch_bounds__(256, 3)
void gemm_bt(const u16* __restrict__ A, const u16* __restrict__ Bt,
             const float* __restrict__ bias, u16* __restrict__ Out,
             int N, int K, int klen, size_t zstride) {
  const int tid = threadIdx.x;
  const int bm = blockIdx.x, bn = blockIdx.y;
  const int wave = tid >> 6, lane = tid & 63;
  const int wm = (wave & 1) * 64, wn = (wave >> 1) * 64;
  const int lr = lane & 15, lq = lane >> 4;

  // fragment bases: 16 rows (lr) x 16B (lq*8 elems), 64B sectors fully used
  const u16* Ag = A + (size_t)(bm * 128 + wm + lr) * K + lq * 8;
  const u16* Bg = Bt + (size_t)(bn * 128 + wn + lr) * K + lq * 8;

  f32x4 acc[4][4];
#pragma unroll
  for (int i = 0; i < 4; i++)
#pragma unroll
    for (int j = 0; j < 4; j++) acc[i][j] = (f32x4){0.f, 0.f, 0.f, 0.f};

  auto loadF = [&](bf16x8* a, bf16x8* b, int k0) {
#pragma unroll
    for (int i = 0; i < 4; i++)
      a[i] = *(const bf16x8*)(Ag + (size_t)(i * 16) * K + k0);
#pragma unroll
    for (int j = 0; j < 4; j++)
      b[j] = *(const bf16x8*)(Bg + (size_t)(j * 16) * K + k0);
  };
  auto compute = [&](const bf16x8* a, const bf16x8* b) {
#pragma unroll
    for (int i = 0; i < 4; i++)
#pragma unroll
      for (int j = 0; j < 4; j++)
        acc[i][j] = __builtin_amdgcn_mfma_f32_16x16x32_bf16(a[i], b[j], acc[i][j], 0, 0, 0);
  };

  const int kbeg = blockIdx.z * klen;
  const int nIter = klen >> 5;   // even (>=12)
  bf16x8 a0[4], b0[4], a1[4], b1[4];
  loadF(a0, b0, kbeg);
  for (int it = 0; it < nIter; it += 2) {
    if (it + 1 < nIter) loadF(a1, b1, kbeg + (it + 1) * 32);
    compute(a0, b0);
    if (it + 2 < nIter) loadF(a0, b0, kbeg + (it + 2) * 32);
    compute(a1, b1);
  }

  u16* Op = Out + blockIdx.z * zstride;
  // C/D layout: col = lane&15, row = (lane>>4)*4 + reg  [verified m89/m91]
  const int r0 = bm * 128 + wm + lq * 4;
  const int c0 = bn * 128 + wn + lr;
  float bv[4];
  if (GELU) {
#pragma unroll
    for (int j = 0; j < 4; j++) bv[j] = bias[c0 + j * 16];
  }
#pragma unroll
  for (int i = 0; i < 4; i++) {
#pragma unroll
    for (int r = 0; r < 4; r++) {
      const size_t rowoff = (size_t)(r0 + i * 16 + r) * N;
#pragma unroll
      for (int j = 0; j < 4; j++) {
        float v = acc[i][j][r];
        if (GELU) {
          v += bv[j];
          v = 0.5f * v * (1.f + erff(v * 0.70710678118654752f));
        }
        Op[rowoff + c0 + j * 16] = f2bf(v);
      }
    }
  }
}

extern "C" void kernel_launch(void* const* d_in, const int* in_sizes, int n_in,
                              void* d_out, int out_size, void* d_ws, size_t ws_size,
                              hipStream_t stream) {
  const float* x   = (const float*)d_in[0];
  const float* g1a = (const float*)d_in[1];
  const float* g1b = (const float*)d_in[2];
  const float* g1c = (const float*)d_in[3];
  const float* g1d = (const float*)d_in[4];
  const float* b1  = (const float*)d_in[5];
  const float* g2a = (const float*)d_in[6];
  const float* g2b = (const float*)d_in[7];
  const float* g2c = (const float*)d_in[8];
  const float* g2d = (const float*)d_in[9];
  const float* b2  = (const float*)d_in[10];
  float* out = (float*)d_out;

  char* ws = (char*)d_ws;
  u16* xb   = (u16*)(ws + 0);          // 4096x768 bf16   = 6291456 B
  u16* W1t  = (u16*)(ws + 6291456);    // 3072x768 bf16   = 4718592 B
  u16* W2t  = (u16*)(ws + 11010048);   // 768x3072 bf16   = 4718592 B
  u16* h    = (u16*)(ws + 15728640);   // 4096x3072 bf16  = 25165824 B
  u16* Part = (u16*)(ws + 40894464);   // nz x 4096x768 bf16
  // TT scratch ALIASES Part (dead before gemm2 writes Part; stream-ordered)
  float* B12_1 = (float*)(ws + 40894464);            // 9216 f32
  float* B12_2 = (float*)(ws + 40894464 + 36864);    // 9216 f32
  float* C1    = (float*)(ws + 40894464 + 73728);    // 147456 f32
  float* C2    = (float*)(ws + 40894464 + 663552);   // 147456 f32

  // split-K factor for GEMM2, guarded by workspace size
  const int nz = (ws_size >= 40894464ull + 8ull * 6291456ull) ? 8 : 4;

  // x->bf16 (blocks 0..3071) + TT pre-pass (blocks 3072..4295)
  prep<<<4296, 256, 0, stream>>>((const float4*)x, (ushort4*)xb,
                                 g1a, g1b, g1c, g1d, g2a, g2b, g2c, g2d,
                                 B12_1, B12_2, C1, C2);

  // merged expand: layer1 (blocks 0..287) + layer2 (blocks 288..575)
  tt_expand2<<<576, 256, 0, stream>>>(B12_1, C1, W1t, B12_2, C2, W2t);

  // GEMM1: h = gelu(x @ W1 + b1)   (4096 x 3072, K=768), 768 blocks = 3/CU
  gemm_bt<true><<<dim3(32, 24, 1), 256, 0, stream>>>(xb, W1t, b1, h, 3072, 768, 768, 0);
  // GEMM2: bf16 partials, K=3072 split nz ways
  gemm_bt<false><<<dim3(32, 6, nz), 256, 0, stream>>>(h, W2t, nullptr, Part,
                                                      768, 3072, 3072 / nz, 3145728);
  // out = b2 + sum(partials)
  reduceN8<<<1536, 256, 0, stream>>>((const uint4*)Part, b2,
                                     (float4*)out, 393216, 393216, nz);
}

// Round 14
// 174.590 us; speedup vs baseline: 1.4996x; 1.4783x over previous
//
#include <hip/hip_runtime.h>
#include <cstdint>
#include <cstddef>

typedef unsigned short u16;
typedef __attribute__((ext_vector_type(8))) __bf16 bf16x8;
typedef __attribute__((ext_vector_type(4))) float f32x4;

__device__ __forceinline__ u16 f2bf(float f) {
  unsigned u = __float_as_uint(f);
  u += 0x7FFFu + ((u >> 16) & 1u);   // round-to-nearest-even
  return (u16)(u >> 16);
}

__device__ __forceinline__ float bf2f(u16 h) {
  return __uint_as_float(((unsigned)h) << 16);
}

__device__ __forceinline__ void async16(u16* lds, const u16* g) {
  __builtin_amdgcn_global_load_lds(
      (const __attribute__((address_space(1))) unsigned int*)g,
      (__attribute__((address_space(3))) unsigned int*)lds, 16, 0, 0);
}

// ---------------- prep: x->bf16 (blocks 0..3071) + TT pre-pass (blocks 3072..4295) ----
__global__ __launch_bounds__(256)
void prep(const float4* __restrict__ x4, ushort4* __restrict__ xb4,
          const float* __restrict__ gA1, const float* __restrict__ gB1,
          const float* __restrict__ gC1, const float* __restrict__ gD1,
          const float* __restrict__ gA2, const float* __restrict__ gB2,
          const float* __restrict__ gC2, const float* __restrict__ gD2,
          float* __restrict__ B12_1, float* __restrict__ B12_2,
          float* __restrict__ C1, float* __restrict__ C2) {
  const int b = blockIdx.x;
  const int tid = threadIdx.x;
  if (b < 3072) {
    int i = b * 256 + tid;
    float4 v = x4[i];
    ushort4 o;
    o.x = f2bf(v.x); o.y = f2bf(v.y); o.z = f2bf(v.z); o.w = f2bf(v.w);
    xb4[i] = o;
    return;
  }
  int idx = (b - 3072) * 256 + tid;
  if (idx < 9216) {
    int e = idx;
    int r2 = e % 24; int t = e / 24;
    int fo12 = t % 24, fi12 = t / 24;
    int i2 = fi12 % 4, i1 = fi12 / 4;
    int o2 = fo12 % 6, o1 = fo12 / 6;
    float s = 0.f;
#pragma unroll
    for (int r1 = 0; r1 < 12; ++r1)
      s += gA1[(i1 * 4 + o1) * 12 + r1] * gB1[((r1 * 4 + i2) * 6 + o2) * 24 + r2];
    B12_1[e] = s;
  } else if (idx < 18432) {
    int e = idx - 9216;
    int r2 = e % 24; int t = e / 24;
    int fo12 = t % 16, fi12 = t / 16;
    int i2 = fi12 % 6, i1 = fi12 / 6;
    int o2 = fo12 % 4, o1 = fo12 / 4;
    float s = 0.f;
#pragma unroll
    for (int r1 = 0; r1 < 12; ++r1)
      s += gA2[(i1 * 4 + o1) * 12 + r1] * gB2[((r1 * 6 + i2) * 4 + o2) * 24 + r2];
    B12_2[e] = s;
  } else if (idx < 165888) {
    int e = idx - 18432;
    int fi34 = e % 48; int t = e / 48;
    int fo34 = t % 128;
    int i3 = fi34 / 8, i4 = fi34 % 8;
    int o3 = fo34 / 16, o4 = fo34 % 16;
    int r2 = t / 128;
    float s = 0.f;
#pragma unroll
    for (int r3 = 0; r3 < 12; ++r3)
      s += gC1[((r2 * 6 + i3) * 8 + o3) * 12 + r3] * gD1[(r3 * 8 + i4) * 16 + o4];
    C1[e] = s;
  } else {
    int e = idx - 165888;
    int fi34 = e % 128; int t = e / 128;
    int fo34 = t % 48;
    int i3 = fi34 / 16, i4 = fi34 % 16;
    int o3 = fo34 / 8, o4 = fo34 % 8;
    int r2 = t / 48;
    float s = 0.f;
#pragma unroll
    for (int r3 = 0; r3 < 12; ++r3)
      s += gC2[((r2 * 8 + i3) * 6 + o3) * 12 + r3] * gD2[(r3 * 16 + i4) * 8 + o4];
    C2[e] = s;
  }
}

// ---------------- TT expand (device body): Wt[out][in] = sum_r2 B12*C34t ----------------
template <int FI12, int I34, int O12, int O34, int OG>
__device__ __forceinline__
void tt_expand_body(const float* __restrict__ B12, const float* __restrict__ C34t,
                    u16* __restrict__ Wt, int bx, int by, int tid, float* sB) {
  constexpr int R2 = 24;
  constexpr int Kin = FI12 * I34;
  constexpr int IC = Kin / 8;
  constexpr int I34C = I34 / 8;
  for (int e = tid; e < FI12 * OG * R2; e += 256) {
    int r2 = e % R2; int t = e / R2;
    int f = t % OG; int fi12 = t / OG;
    sB[(fi12 * OG + f) * 25 + r2] = B12[(fi12 * O12 + by * OG + f) * R2 + r2];
  }
  __syncthreads();
  const int t = bx * 256 + tid;
  const int fo34 = t / IC;
  const int ic = t % IC;
  const int fi12 = ic / I34C;
  const int fi34 = (ic % I34C) * 8;

  float acc[OG][8];
#pragma unroll
  for (int f = 0; f < OG; ++f)
#pragma unroll
    for (int k = 0; k < 8; ++k) acc[f][k] = 0.f;

  for (int r2 = 0; r2 < R2; ++r2) {
    const float4* cp = (const float4*)(C34t + ((size_t)(r2 * O34 + fo34) * I34 + fi34));
    float4 c0 = cp[0], c1 = cp[1];
    float c[8] = {c0.x, c0.y, c0.z, c0.w, c1.x, c1.y, c1.z, c1.w};
#pragma unroll
    for (int f = 0; f < OG; ++f) {
      float bb = sB[(fi12 * OG + f) * 25 + r2];
#pragma unroll
      for (int k = 0; k < 8; ++k) acc[f][k] += bb * c[k];
    }
  }
#pragma unroll
  for (int f = 0; f < OG; ++f) {
    int out = (by * OG + f) * O34 + fo34;
    u16 v[8];
#pragma unroll
    for (int k = 0; k < 8; ++k) v[k] = f2bf(acc[f][k]);
    *(uint4*)(Wt + (size_t)out * Kin + fi12 * I34 + fi34) = *(const uint4*)v;
  }
}

// Merged: blocks 0..287 -> layer1 (48x6); blocks 288..575 -> layer2 (72x4)
__global__ __launch_bounds__(256)
void tt_expand2(const float* __restrict__ B12_1, const float* __restrict__ C1, u16* __restrict__ W1t,
                const float* __restrict__ B12_2, const float* __restrict__ C2, u16* __restrict__ W2t) {
  __shared__ float sB[24 * 4 * 25];
  const int b = blockIdx.x;
  const int tid = threadIdx.x;
  if (b < 288) {
    tt_expand_body<16, 48, 24, 128, 4>(B12_1, C1, W1t, b % 48, b / 48, tid, sB);
  } else {
    int bb = b - 288;
    tt_expand_body<24, 128, 16, 48, 4>(B12_2, C2, W2t, bb % 72, bb / 72, tid, sB);
  }
}

// out = bias2 + sum of nz bf16 partials; 8 elems/thread, 16B partial loads
__global__ void reduceN8(const uint4* __restrict__ P, const float* __restrict__ bias,
                         float4* __restrict__ out4, int n8, int zstride8, int nz) {
  int i = blockIdx.x * 256 + threadIdx.x;
  if (i >= n8) return;
  int b0 = (i % 96) * 8;
  float a[8];
#pragma unroll
  for (int k = 0; k < 8; ++k) a[k] = bias[b0 + k];
  for (int s = 0; s < nz; ++s) {
    uint4 u = P[i + s * zstride8];
    const u16* up = (const u16*)&u;
#pragma unroll
    for (int k = 0; k < 8; ++k) a[k] += bf2f(up[k]);
  }
  out4[i * 2]     = (float4){a[0], a[1], a[2], a[3]};
  out4[i * 2 + 1] = (float4){a[4], a[5], a[6], a[7]};
}

// ---------------- bf16 MFMA GEMM, C = A(MxK) * Bt(NxK)^T, R9 structure ----------------
// Best measured config across R9-R13 by the clock-invariant metric
// dur*MfmaUtil: LDS double-buffer BOTH operands (global_load_lds width16),
// BK=32, 128x128 tile, 1 barrier per iter, MINW=3 (56 VGPR + 64 AGPR; MINW>=5
// spills acc, R5), j-inner epilogue (R7/R8 A/B: faster + 2.4x less HBM write).
// B-direct (R11), smaller tile (R12), no-LDS (R13) all LOWERED MfmaUtil.
// 1D grid + XCD-aware swizzle: blockIdx.x&7 ~ XCD; give each XCD a fixed
// 3-wide bn stripe so its 4MB L2 holds 590KB of Bt instead of cycling 4.7MB.
// NB: swizzle is locality-only (any block->XCD mapping stays correct).
template <bool GELU>
__global__ __launch_bounds__(256, 3)
void gemm_bt(const u16* __restrict__ A, const u16* __restrict__ Bt,
             const float* __restrict__ bias, u16* __restrict__ Out,
             int N, int K, int klen, size_t zstride, int NBN) {
  // decode swizzled 1D id -> (bm, bn, bz): 8 XCD stripes x 3 (bn,z)-combos x 32 bm
  const int flat = blockIdx.x;
  const int xcd = flat & 7;
  const int local = flat >> 3;
  const int combo = xcd * 3 + local % 3;       // 0..23 = (bn,z) combos
  const int bm = local / 3;                    // 0..31
  const int bn = combo % NBN;
  const int bz = combo / NBN;

  __shared__ __align__(16) u16 As[2][128 * 32];
  __shared__ __align__(16) u16 Bs[2][128 * 32];
  const int tid = threadIdx.x;
  const int wave = tid >> 6, lane = tid & 63;
  const int wm = (wave & 1) * 64, wn = (wave >> 1) * 64;
  const int lr = lane & 15, lq = lane >> 4;

  const int srow = tid >> 2;
  const int scol = (tid & 3) * 8;
  const u16* Ag = A + (size_t)(bm * 128 + srow) * K + scol;
  const u16* Bg = Bt + (size_t)(bn * 128 + srow) * K + scol;
  u16* AsW = &As[0][0] + tid * 8;
  u16* BsW = &Bs[0][0] + tid * 8;

  f32x4 acc[4][4];
#pragma unroll
  for (int i = 0; i < 4; i++)
#pragma unroll
    for (int j = 0; j < 4; j++) acc[i][j] = (f32x4){0.f, 0.f, 0.f, 0.f};

  const int kbeg = bz * klen;
  const int nIter = klen >> 5;   // even

  auto stage = [&](int buf, int k0) {
    async16(AsW + buf * 4096,        Ag + k0);
    async16(AsW + buf * 4096 + 2048, Ag + k0 + (size_t)64 * K);
    async16(BsW + buf * 4096,        Bg + k0);
    async16(BsW + buf * 4096 + 2048, Bg + k0 + (size_t)64 * K);
  };
  auto compute = [&](int buf) {
    bf16x8 af[4], bfr[4];
#pragma unroll
    for (int i = 0; i < 4; i++)
      af[i] = *(const bf16x8*)(&As[buf][0] + (wm + i * 16 + lr) * 32 + lq * 8);
#pragma unroll
    for (int j = 0; j < 4; j++)
      bfr[j] = *(const bf16x8*)(&Bs[buf][0] + (wn + j * 16 + lr) * 32 + lq * 8);
#pragma unroll
    for (int i = 0; i < 4; i++)
#pragma unroll
      for (int j = 0; j < 4; j++)
        acc[i][j] = __builtin_amdgcn_mfma_f32_16x16x32_bf16(af[i], bfr[j], acc[i][j], 0, 0, 0);
  };

  stage(0, kbeg);                      // prologue
  for (int it = 0; it < nIter; it += 2) {
    __syncthreads();                   // buf0 staged; buf1 readers done
    if (it + 1 < nIter) stage(1, kbeg + (it + 1) * 32);
    compute(0);
    __syncthreads();                   // buf1 staged; buf0 readers done
    if (it + 2 < nIter) stage(0, kbeg + (it + 2) * 32);
    compute(1);
  }

  u16* Op = Out + (size_t)bz * zstride;
  // C/D layout: col = lane&15, row = (lane>>4)*4 + reg  [verified m89/m91]
  const int r0 = bm * 128 + wm + lq * 4;
  const int c0 = bn * 128 + wn + lr;
  float bv[4];
  if (GELU) {
#pragma unroll
    for (int j = 0; j < 4; j++) bv[j] = bias[c0 + j * 16];
  }
#pragma unroll
  for (int i = 0; i < 4; i++) {
#pragma unroll
    for (int r = 0; r < 4; r++) {
      const size_t rowoff = (size_t)(r0 + i * 16 + r) * N;
#pragma unroll
      for (int j = 0; j < 4; j++) {
        float v = acc[i][j][r];
        if (GELU) {
          v += bv[j];
          v = 0.5f * v * (1.f + erff(v * 0.70710678118654752f));
        }
        Op[rowoff + c0 + j * 16] = f2bf(v);
      }
    }
  }
}

extern "C" void kernel_launch(void* const* d_in, const int* in_sizes, int n_in,
                              void* d_out, int out_size, void* d_ws, size_t ws_size,
                              hipStream_t stream) {
  const float* x   = (const float*)d_in[0];
  const float* g1a = (const float*)d_in[1];
  const float* g1b = (const float*)d_in[2];
  const float* g1c = (const float*)d_in[3];
  const float* g1d = (const float*)d_in[4];
  const float* b1  = (const float*)d_in[5];
  const float* g2a = (const float*)d_in[6];
  const float* g2b = (const float*)d_in[7];
  const float* g2c = (const float*)d_in[8];
  const float* g2d = (const float*)d_in[9];
  const float* b2  = (const float*)d_in[10];
  float* out = (float*)d_out;

  char* ws = (char*)d_ws;
  u16* xb   = (u16*)(ws + 0);          // 4096x768 bf16   = 6291456 B
  u16* W1t  = (u16*)(ws + 6291456);    // 3072x768 bf16   = 4718592 B
  u16* W2t  = (u16*)(ws + 11010048);   // 768x3072 bf16   = 4718592 B
  u16* h    = (u16*)(ws + 15728640);   // 4096x3072 bf16  = 25165824 B
  u16* Part = (u16*)(ws + 40894464);   // 4 x 4096x768 bf16
  // TT scratch ALIASES Part (dead before gemm2 writes Part; stream-ordered)
  float* B12_1 = (float*)(ws + 40894464);            // 9216 f32
  float* B12_2 = (float*)(ws + 40894464 + 36864);    // 9216 f32
  float* C1    = (float*)(ws + 40894464 + 73728);    // 147456 f32
  float* C2    = (float*)(ws + 40894464 + 663552);   // 147456 f32

  // x->bf16 (blocks 0..3071) + TT pre-pass (blocks 3072..4295)
  prep<<<4296, 256, 0, stream>>>((const float4*)x, (ushort4*)xb,
                                 g1a, g1b, g1c, g1d, g2a, g2b, g2c, g2d,
                                 B12_1, B12_2, C1, C2);

  // merged expand: layer1 (blocks 0..287) + layer2 (blocks 288..575)
  tt_expand2<<<576, 256, 0, stream>>>(B12_1, C1, W1t, B12_2, C2, W2t);

  // GEMM1: h = gelu(x @ W1 + b1)  (4096x3072, K=768); 768 blocks, 24 combos = 24 bn x 1 z
  gemm_bt<true><<<768, 256, 0, stream>>>(xb, W1t, b1, h, 3072, 768, 768, 0, 24);
  // GEMM2: bf16 partials, K=3072 split 4 ways; 768 blocks, 24 combos = 6 bn x 4 z
  gemm_bt<false><<<768, 256, 0, stream>>>(h, W2t, nullptr, Part, 768, 3072, 768, 3145728, 6);
  // out = b2 + sum(partials)
  reduceN8<<<1536, 256, 0, stream>>>((const uint4*)Part, b2,
                                     (float4*)out, 393216, 393216, 4);
}